// Round 3
// baseline (328.831 us; speedup 1.0000x reference)
//
#include <hip/hip_runtime.h>
#include <stdint.h>

// Bahdanau additive attention, MI355X / gfx950.
// Inputs fp32, OUTPUTS fp32 (reference output dtype — R2 post-mortem).
// B=32, T=2048, D=512, U=512.  M = B*T = 65536.
//
// Pipeline:
//   memset lg+ctx -> 0
//   [big ws] convert_feats : fp32 -> bf16 copy of features (64 MB in ws)
//   prep_uh   : uh[b][u] = hidden[b]·Uk[:,u] + Ub[u] + Wb[u]            (fp32)
//   prep_wkt  : WkT[u][d] = bf16(Wk[d][u])
//   attn_gemm : lg[m] += sum_{u in chunk} tanh(F[m]·Wk[:,u]+uh[b][u])*Vk[u]
//               (bf16 MFMA 16x16x32, 128x128 tile, N split over 4 blocks)
//   softmax_k : aw = softmax_T(lg) -> fp32 directly into d_out
//   context_k : ctx[b][d] += sum_t aw*F (fp32 atomics, ws)
//   ctx_out_k : ctx -> fp32 out
// Vb is a constant logit shift -> cancels in softmax; unused.

typedef unsigned short ushort_t;
typedef __attribute__((ext_vector_type(8))) short short8;
typedef __attribute__((ext_vector_type(4))) float f32x4;
typedef __attribute__((ext_vector_type(2))) float float2v;
typedef __attribute__((ext_vector_type(2))) __bf16 bf162v;

#define GLOBAL_AS __attribute__((address_space(1)))
#define LDS_AS    __attribute__((address_space(3)))

__device__ __forceinline__ ushort_t f2bf(float f) {
    uint32_t u = __builtin_bit_cast(uint32_t, f);
    u = (u + 0x7fffu + ((u >> 16) & 1u)) >> 16;   // RNE
    return (ushort_t)u;
}
__device__ __forceinline__ uint32_t pkbf(float a, float b) {
    bf162v r = __builtin_convertvector((float2v){a, b}, bf162v);  // RNE pair cvt
    return __builtin_bit_cast(uint32_t, r);
}

// ------------------------------------------------- fp32 -> bf16 features copy
__global__ __launch_bounds__(256) void convert_feats(
    const float* __restrict__ f, ushort_t* __restrict__ o)
{
    const size_t i = ((size_t)blockIdx.x * 256 + threadIdx.x) * 8;
    f32x4 a = *(const f32x4*)(f + i);
    f32x4 b = *(const f32x4*)(f + i + 4);
    union { short8 s; uint32_t u[4]; } r;
    r.u[0] = pkbf(a.x, a.y); r.u[1] = pkbf(a.z, a.w);
    r.u[2] = pkbf(b.x, b.y); r.u[3] = pkbf(b.z, b.w);
    *(short8*)(o + i) = r.s;
}

// ---------------------------------------------------------------- prep: uh
__global__ __launch_bounds__(256) void prep_uh(
    const float* __restrict__ hidden, const float* __restrict__ Uk,
    const float* __restrict__ Ub, const float* __restrict__ Wb,
    float* __restrict__ uh)
{
    const int b = blockIdx.x >> 1;
    const int u = ((blockIdx.x & 1) << 8) + threadIdx.x;
    const float* hr = hidden + b * 512;
    float acc = Ub[u] + Wb[u];
    #pragma unroll 8
    for (int h = 0; h < 512; ++h)
        acc += hr[h] * Uk[h * 512 + u];
    uh[b * 512 + u] = acc;
}

// ------------------------------------------------------- prep: Wk transpose
__global__ __launch_bounds__(256) void prep_wkt(
    const float* __restrict__ Wk, ushort_t* __restrict__ WkT)
{
    const int u = blockIdx.x;
    const int d = threadIdx.x;
    WkT[u * 512 + d]       = f2bf(Wk[d * 512 + u]);
    WkT[u * 512 + d + 256] = f2bf(Wk[(d + 256) * 512 + u]);
}

// ------------------------------------------------ fused GEMM+tanh+Vk-dot
// grid 2048 = 512 M-blocks x 4 N-chunks; 256 threads (4 waves, 2x2).
// CONV=true : A staged fp32->bf16 via VGPR (small-ws fallback)
// CONV=false: A pre-converted bf16, async global_load_lds (big-ws path)
template<bool CONV>
__global__ __launch_bounds__(256) void attn_gemm(
    const float* __restrict__ afp, const ushort_t* __restrict__ abf,
    const ushort_t* __restrict__ WkT, const float* __restrict__ uh,
    const float* __restrict__ Vk, float* __restrict__ lg)
{
    __shared__ __align__(16) short As[128 * 32];
    __shared__ __align__(16) short Bs[128 * 32];
    __shared__ float uh_s[128];
    __shared__ float vk_s[128];
    __shared__ float lpart[2][128];

    const int tid  = threadIdx.x;
    const int lane = tid & 63;
    const int quad = lane >> 4;
    const int lc   = lane & 15;
    const int wave = tid >> 6;
    const int wm   = wave >> 1;
    const int wn   = wave & 1;
    const int mblk = blockIdx.x >> 2;
    const int nc   = blockIdx.x & 3;
    const int m0   = mblk * 128;
    const int bidx = m0 >> 11;       // batch index (uniform per block)

    if (tid < 128) {
        uh_s[tid] = uh[bidx * 512 + nc * 128 + tid];
        vk_s[tid] = Vk[nc * 128 + tid];
    }

    f32x4 acc[4][4];
    #pragma unroll
    for (int tm = 0; tm < 4; ++tm)
        #pragma unroll
        for (int tn = 0; tn < 4; ++tn)
            acc[tm][tn] = (f32x4){0.f, 0.f, 0.f, 0.f};

    for (int ks = 0; ks < 16; ++ks) {   // K = 512, BK = 32
        const int k0 = ks * 32;
        __syncthreads();
        // ---- B tile (bf16 WkT), async 16B direct-to-LDS
        {
            const int rowB = tid >> 2;
            const int kqB  = (tid & 3) * 8;
            #pragma unroll
            for (int rnd = 0; rnd < 2; ++rnd) {
                const int li  = rnd * 256 + tid;
                const int row = rnd * 64 + rowB;
                const ushort_t* gb = WkT + (size_t)(nc * 128 + row) * 512 + k0 + kqB;
                __builtin_amdgcn_global_load_lds(
                    (const GLOBAL_AS void*)gb, (LDS_AS void*)(Bs + li * 8), 16, 0, 0);
            }
        }
        // ---- A tile
        if constexpr (CONV) {
            const int row = tid >> 1;
            const int k16 = (tid & 1) * 16;
            const float* ga = afp + (size_t)(m0 + row) * 512 + k0 + k16;
            f32x4 a0 = *(const f32x4*)(ga);
            f32x4 a1 = *(const f32x4*)(ga + 4);
            f32x4 a2 = *(const f32x4*)(ga + 8);
            f32x4 a3 = *(const f32x4*)(ga + 12);
            union { short8 s; uint32_t u[4]; } r0, r1;
            r0.u[0] = pkbf(a0.x, a0.y); r0.u[1] = pkbf(a0.z, a0.w);
            r0.u[2] = pkbf(a1.x, a1.y); r0.u[3] = pkbf(a1.z, a1.w);
            r1.u[0] = pkbf(a2.x, a2.y); r1.u[1] = pkbf(a2.z, a2.w);
            r1.u[2] = pkbf(a3.x, a3.y); r1.u[3] = pkbf(a3.z, a3.w);
            *(short8*)(As + row * 32 + k16)     = r0.s;
            *(short8*)(As + row * 32 + k16 + 8) = r1.s;
        } else {
            const int rowA = tid >> 2;
            const int kqA  = (tid & 3) * 8;
            #pragma unroll
            for (int rnd = 0; rnd < 2; ++rnd) {
                const int li  = rnd * 256 + tid;
                const int row = rnd * 64 + rowA;
                const ushort_t* ga = abf + (size_t)(m0 + row) * 512 + k0 + kqA;
                __builtin_amdgcn_global_load_lds(
                    (const GLOBAL_AS void*)ga, (LDS_AS void*)(As + li * 8), 16, 0, 0);
            }
        }
        __syncthreads();

        short8 af[4], bfr[4];
        #pragma unroll
        for (int t4 = 0; t4 < 4; ++t4) {
            af[t4]  = *(const short8*)(As + (wm * 64 + t4 * 16 + lc) * 32 + quad * 8);
            bfr[t4] = *(const short8*)(Bs + (wn * 64 + t4 * 16 + lc) * 32 + quad * 8);
        }
        #pragma unroll
        for (int tm = 0; tm < 4; ++tm)
            #pragma unroll
            for (int tn = 0; tn < 4; ++tn)
                acc[tm][tn] = __builtin_amdgcn_mfma_f32_16x16x32_bf16(
                    af[tm], bfr[tn], acc[tm][tn], 0, 0, 0);
    }

    // epilogue: tanh(acc + uh) * Vk, fold into per-row partials
    // C/D layout: col = lane&15, row = quad*4 + reg   [m89-verified]
    float rp[16];
    #pragma unroll
    for (int i = 0; i < 16; ++i) rp[i] = 0.f;
    #pragma unroll
    for (int tn = 0; tn < 4; ++tn) {
        const int nl  = wn * 64 + tn * 16 + lc;
        const float uhv = uh_s[nl];
        const float vkv = vk_s[nl];
        #pragma unroll
        for (int tm = 0; tm < 4; ++tm)
            #pragma unroll
            for (int i = 0; i < 4; ++i) {
                const float x = acc[tm][tn][i] + uhv;
                const float e = __expf(2.0f * x);          // tanh = 1 - 2/(e^{2x}+1)
                rp[tm * 4 + i] += (1.0f - 2.0f / (e + 1.0f)) * vkv;
            }
    }
    // reduce across the 16 column-lanes (xor bits 0..3 keep quad fixed)
    #pragma unroll
    for (int i = 0; i < 16; ++i) {
        float v = rp[i];
        v += __shfl_xor(v, 1, 64);
        v += __shfl_xor(v, 2, 64);
        v += __shfl_xor(v, 4, 64);
        v += __shfl_xor(v, 8, 64);
        rp[i] = v;
    }
    if (lc == 0) {
        #pragma unroll
        for (int tm = 0; tm < 4; ++tm)
            #pragma unroll
            for (int i = 0; i < 4; ++i)
                lpart[wn][wm * 64 + tm * 16 + quad * 4 + i] = rp[tm * 4 + i];
    }
    __syncthreads();
    if (tid < 128)
        atomicAdd(&lg[m0 + tid], lpart[0][tid] + lpart[1][tid]);
}

// ---------------------------------------------------------------- softmax
__global__ __launch_bounds__(256) void softmax_k(
    const float* __restrict__ lg, float* __restrict__ aw_out)
{
    const int b = blockIdx.x, tid = threadIdx.x;
    const float* p = lg + b * 2048;
    float v[8];
    #pragma unroll
    for (int i = 0; i < 8; ++i) v[i] = p[tid + i * 256];
    float mx = -1e30f;
    #pragma unroll
    for (int i = 0; i < 8; ++i) mx = fmaxf(mx, v[i]);
    #pragma unroll
    for (int off = 32; off >= 1; off >>= 1) mx = fmaxf(mx, __shfl_xor(mx, off, 64));
    __shared__ float redm[4], reds[4];
    const int wv = tid >> 6, ln = tid & 63;
    if (ln == 0) redm[wv] = mx;
    __syncthreads();
    mx = fmaxf(fmaxf(redm[0], redm[1]), fmaxf(redm[2], redm[3]));
    float s = 0.f;
    #pragma unroll
    for (int i = 0; i < 8; ++i) { v[i] = __expf(v[i] - mx); s += v[i]; }
    #pragma unroll
    for (int off = 32; off >= 1; off >>= 1) s += __shfl_xor(s, off, 64);
    if (ln == 0) reds[wv] = s;
    __syncthreads();
    s = reds[0] + reds[1] + reds[2] + reds[3];
    const float inv = 1.0f / s;
    #pragma unroll
    for (int i = 0; i < 8; ++i)
        aw_out[b * 2048 + tid + i * 256] = v[i] * inv;   // fp32 output
}

// ------------------------------------------------------- context reduction
__global__ __launch_bounds__(256) void context_k(
    const float* __restrict__ feats, const float* __restrict__ aw,
    float* __restrict__ ctx)
{
    const int blk = blockIdx.x;
    const int b  = blk >> 6;
    const int t0 = (blk & 63) * 32;
    const int d  = threadIdx.x * 2;
    const float* fp = feats + (size_t)(b * 2048 + t0) * 512 + d;
    const float* wp = aw + b * 2048 + t0;
    float a0 = 0.f, a1 = 0.f;
    #pragma unroll 4
    for (int tt = 0; tt < 32; ++tt) {
        const float w = wp[tt];
        const float2v f2 = *(const float2v*)(fp + (size_t)tt * 512);
        a0 += w * f2.x;
        a1 += w * f2.y;
    }
    atomicAdd(&ctx[b * 512 + d],     a0);
    atomicAdd(&ctx[b * 512 + d + 1], a1);
}

__global__ __launch_bounds__(256) void ctx_out_k(
    const float* __restrict__ ctx, float* __restrict__ out)
{
    const int i = blockIdx.x * 256 + threadIdx.x;
    out[i] = ctx[i];
}

// ---------------------------------------------------------------- launch
extern "C" void kernel_launch(void* const* d_in, const int* in_sizes, int n_in,
                              void* d_out, int out_size, void* d_ws, size_t ws_size,
                              hipStream_t stream)
{
    const float* feats  = (const float*)d_in[0];
    const float* hidden = (const float*)d_in[1];
    const float* Wk     = (const float*)d_in[2];
    const float* Wb     = (const float*)d_in[3];
    const float* Uk     = (const float*)d_in[4];
    const float* Ub     = (const float*)d_in[5];
    const float* Vk     = (const float*)d_in[6];
    // d_in[7] = Vb: constant logit shift, cancels in softmax.

    float* out       = (float*)d_out;
    float* ctx_out_p = out;               // [32*512]  fp32
    float* aw_out_p  = out + 16384;       // [32*2048] fp32

    char* ws = (char*)d_ws;
    float*    uh  = (float*)ws;                               // 64 KB
    ushort_t* WkT = (ushort_t*)(ws + 65536);                  // 512 KB
    float*    lg  = (float*)(ws + 65536 + 524288);            // 256 KB
    float*    ctx = (float*)(ws + 65536 + 524288 + 262144);   // 64 KB
    ushort_t* fbf = (ushort_t*)(ws + (1 << 20));              // 64 MB (big path)

    const bool bigws = ws_size >= ((1ull << 20) + (64ull << 20));

    hipMemsetAsync(lg, 0, 262144 + 65536, stream);            // lg + ctx (adjacent)
    prep_uh  <<<64,  256, 0, stream>>>(hidden, Uk, Ub, Wb, uh);
    prep_wkt <<<512, 256, 0, stream>>>(Wk, WkT);
    if (bigws) {
        convert_feats<<<16384, 256, 0, stream>>>(feats, fbf);
        attn_gemm<false><<<2048, 256, 0, stream>>>(feats, fbf, WkT, uh, Vk, lg);
    } else {
        attn_gemm<true><<<2048, 256, 0, stream>>>(feats, (const ushort_t*)nullptr,
                                                  WkT, uh, Vk, lg);
    }
    softmax_k<<<32,   256, 0, stream>>>(lg, aw_out_p);
    context_k<<<2048, 256, 0, stream>>>(feats, aw_out_p, ctx);
    ctx_out_k<<<64,   256, 0, stream>>>(ctx, ctx_out_p);
}

// Round 4
// 312.747 us; speedup vs baseline: 1.0514x; 1.0514x over previous
//
#include <hip/hip_runtime.h>
#include <stdint.h>

// Bahdanau additive attention, MI355X / gfx950.
// Inputs fp32, outputs fp32 (ctx[32*512] ++ aw[32*2048]).
// B=32, T=2048, D=512, U=512.  M = B*T = 65536.
//
// R4: lg atomics -> 4 partial planes; prep_uh/prep_wkt parallelized/coalesced;
//     context_k float4. GEMM core (m97-style, verified R3) unchanged.

typedef unsigned short ushort_t;
typedef __attribute__((ext_vector_type(8))) short short8;
typedef __attribute__((ext_vector_type(4))) float f32x4;
typedef __attribute__((ext_vector_type(2))) float float2v;
typedef __attribute__((ext_vector_type(2))) __bf16 bf162v;

#define GLOBAL_AS __attribute__((address_space(1)))
#define LDS_AS    __attribute__((address_space(3)))

__device__ __forceinline__ ushort_t f2bf(float f) {
    uint32_t u = __builtin_bit_cast(uint32_t, f);
    u = (u + 0x7fffu + ((u >> 16) & 1u)) >> 16;   // RNE
    return (ushort_t)u;
}
__device__ __forceinline__ uint32_t pkbf(float a, float b) {
    bf162v r = __builtin_convertvector((float2v){a, b}, bf162v);
    return __builtin_bit_cast(uint32_t, r);
}

// ------------------------------------------------- fp32 -> bf16 features copy
__global__ __launch_bounds__(256) void convert_feats(
    const float* __restrict__ f, ushort_t* __restrict__ o)
{
    const size_t i = ((size_t)blockIdx.x * 256 + threadIdx.x) * 8;
    f32x4 a = *(const f32x4*)(f + i);
    f32x4 b = *(const f32x4*)(f + i + 4);
    union { short8 s; uint32_t u[4]; } r;
    r.u[0] = pkbf(a.x, a.y); r.u[1] = pkbf(a.z, a.w);
    r.u[2] = pkbf(b.x, b.y); r.u[3] = pkbf(b.z, b.w);
    *(short8*)(o + i) = r.s;
}

// ---------------------------------------------------------------- prep: uh
// grid 256 = 32 b x 8 u-groups(64); block 256 = 64 u x 4 k-segments(128)
__global__ __launch_bounds__(256) void prep_uh(
    const float* __restrict__ hidden, const float* __restrict__ Uk,
    const float* __restrict__ Ub, const float* __restrict__ Wb,
    float* __restrict__ uh)
{
    const int b  = blockIdx.x >> 3;
    const int u  = (blockIdx.x & 7) * 64 + (threadIdx.x & 63);
    const int k0 = (threadIdx.x >> 6) * 128;
    const float* hr = hidden + b * 512;
    float acc = 0.f;
    #pragma unroll 8
    for (int k = k0; k < k0 + 128; ++k)
        acc += hr[k] * Uk[k * 512 + u];
    __shared__ float red[256];
    red[threadIdx.x] = acc;
    __syncthreads();
    if (threadIdx.x < 64) {
        const int ul = threadIdx.x;
        uh[b * 512 + u] = red[ul] + red[ul + 64] + red[ul + 128] + red[ul + 192]
                        + Ub[u] + Wb[u];
    }
}

// ------------------------------------------------- prep: Wk transpose (LDS)
// grid 256 = 16x16 tiles of 32x32
__global__ __launch_bounds__(256) void prep_wkt(
    const float* __restrict__ Wk, ushort_t* __restrict__ WkT)
{
    __shared__ float t[32][33];
    const int ti = blockIdx.x >> 4;   // d-tile
    const int tj = blockIdx.x & 15;   // u-tile
    const int tx = threadIdx.x & 31;
    const int ty = threadIdx.x >> 5;  // 0..7
    #pragma unroll
    for (int q = 0; q < 4; ++q) {
        const int r = ty * 4 + q;
        t[r][tx] = Wk[(ti * 32 + r) * 512 + tj * 32 + tx];
    }
    __syncthreads();
    #pragma unroll
    for (int q = 0; q < 4; ++q) {
        const int r = ty * 4 + q;
        WkT[(tj * 32 + r) * 512 + ti * 32 + tx] = f2bf(t[tx][r]);
    }
}

// ------------------------------------------------ fused GEMM+tanh+Vk-dot
// grid 2048 = 512 M-blocks x 4 N-chunks; 256 threads (4 waves, 2x2).
// Partial logits go to lg4[nc][m] (no atomics).
template<bool CONV>
__global__ __launch_bounds__(256) void attn_gemm(
    const float* __restrict__ afp, const ushort_t* __restrict__ abf,
    const ushort_t* __restrict__ WkT, const float* __restrict__ uh,
    const float* __restrict__ Vk, float* __restrict__ lg4)
{
    __shared__ __align__(16) short As[128 * 32];
    __shared__ __align__(16) short Bs[128 * 32];
    __shared__ float uh_s[128];
    __shared__ float vk_s[128];
    __shared__ float lpart[2][128];

    const int tid  = threadIdx.x;
    const int lane = tid & 63;
    const int quad = lane >> 4;
    const int lc   = lane & 15;
    const int wave = tid >> 6;
    const int wm   = wave >> 1;
    const int wn   = wave & 1;
    const int mblk = blockIdx.x >> 2;
    const int nc   = blockIdx.x & 3;
    const int m0   = mblk * 128;
    const int bidx = m0 >> 11;       // batch index (uniform per block)

    if (tid < 128) {
        uh_s[tid] = uh[bidx * 512 + nc * 128 + tid];
        vk_s[tid] = Vk[nc * 128 + tid];
    }

    f32x4 acc[4][4];
    #pragma unroll
    for (int tm = 0; tm < 4; ++tm)
        #pragma unroll
        for (int tn = 0; tn < 4; ++tn)
            acc[tm][tn] = (f32x4){0.f, 0.f, 0.f, 0.f};

    for (int ks = 0; ks < 16; ++ks) {   // K = 512, BK = 32
        const int k0 = ks * 32;
        __syncthreads();
        {   // B tile (bf16 WkT), async 16B direct-to-LDS
            const int rowB = tid >> 2;
            const int kqB  = (tid & 3) * 8;
            #pragma unroll
            for (int rnd = 0; rnd < 2; ++rnd) {
                const int li  = rnd * 256 + tid;
                const int row = rnd * 64 + rowB;
                const ushort_t* gb = WkT + (size_t)(nc * 128 + row) * 512 + k0 + kqB;
                __builtin_amdgcn_global_load_lds(
                    (const GLOBAL_AS void*)gb, (LDS_AS void*)(Bs + li * 8), 16, 0, 0);
            }
        }
        if constexpr (CONV) {   // A tile: fp32 -> bf16 via VGPR (fallback)
            const int row = tid >> 1;
            const int k16 = (tid & 1) * 16;
            const float* ga = afp + (size_t)(m0 + row) * 512 + k0 + k16;
            f32x4 a0 = *(const f32x4*)(ga);
            f32x4 a1 = *(const f32x4*)(ga + 4);
            f32x4 a2 = *(const f32x4*)(ga + 8);
            f32x4 a3 = *(const f32x4*)(ga + 12);
            union { short8 s; uint32_t u[4]; } r0, r1;
            r0.u[0] = pkbf(a0.x, a0.y); r0.u[1] = pkbf(a0.z, a0.w);
            r0.u[2] = pkbf(a1.x, a1.y); r0.u[3] = pkbf(a1.z, a1.w);
            r1.u[0] = pkbf(a2.x, a2.y); r1.u[1] = pkbf(a2.z, a2.w);
            r1.u[2] = pkbf(a3.x, a3.y); r1.u[3] = pkbf(a3.z, a3.w);
            *(short8*)(As + row * 32 + k16)     = r0.s;
            *(short8*)(As + row * 32 + k16 + 8) = r1.s;
        } else {                // A tile: pre-converted bf16, async
            const int rowA = tid >> 2;
            const int kqA  = (tid & 3) * 8;
            #pragma unroll
            for (int rnd = 0; rnd < 2; ++rnd) {
                const int li  = rnd * 256 + tid;
                const int row = rnd * 64 + rowA;
                const ushort_t* ga = abf + (size_t)(m0 + row) * 512 + k0 + kqA;
                __builtin_amdgcn_global_load_lds(
                    (const GLOBAL_AS void*)ga, (LDS_AS void*)(As + li * 8), 16, 0, 0);
            }
        }
        __syncthreads();

        short8 af[4], bfr[4];
        #pragma unroll
        for (int t4 = 0; t4 < 4; ++t4) {
            af[t4]  = *(const short8*)(As + (wm * 64 + t4 * 16 + lc) * 32 + quad * 8);
            bfr[t4] = *(const short8*)(Bs + (wn * 64 + t4 * 16 + lc) * 32 + quad * 8);
        }
        #pragma unroll
        for (int tm = 0; tm < 4; ++tm)
            #pragma unroll
            for (int tn = 0; tn < 4; ++tn)
                acc[tm][tn] = __builtin_amdgcn_mfma_f32_16x16x32_bf16(
                    af[tm], bfr[tn], acc[tm][tn], 0, 0, 0);
    }

    // epilogue: tanh(acc + uh) * Vk -> per-row partials
    // C/D layout: col = lane&15, row = quad*4 + reg   [m89-verified]
    float rp[16];
    #pragma unroll
    for (int i = 0; i < 16; ++i) rp[i] = 0.f;
    #pragma unroll
    for (int tn = 0; tn < 4; ++tn) {
        const int nl  = wn * 64 + tn * 16 + lc;
        const float uhv = uh_s[nl];
        const float vkv = vk_s[nl];
        #pragma unroll
        for (int tm = 0; tm < 4; ++tm)
            #pragma unroll
            for (int i = 0; i < 4; ++i) {
                const float x = acc[tm][tn][i] + uhv;
                const float e = __expf(2.0f * x);          // tanh = 1 - 2/(e^{2x}+1)
                rp[tm * 4 + i] += (1.0f - 2.0f / (e + 1.0f)) * vkv;
            }
    }
    #pragma unroll
    for (int i = 0; i < 16; ++i) {
        float v = rp[i];
        v += __shfl_xor(v, 1, 64);
        v += __shfl_xor(v, 2, 64);
        v += __shfl_xor(v, 4, 64);
        v += __shfl_xor(v, 8, 64);
        rp[i] = v;
    }
    if (lc == 0) {
        #pragma unroll
        for (int tm = 0; tm < 4; ++tm)
            #pragma unroll
            for (int i = 0; i < 4; ++i)
                lpart[wn][wm * 64 + tm * 16 + quad * 4 + i] = rp[tm * 4 + i];
    }
    __syncthreads();
    if (tid < 128)
        lg4[(size_t)nc * 65536 + m0 + tid] = lpart[0][tid] + lpart[1][tid];
}

// ---------------------------------------------------------------- softmax
__global__ __launch_bounds__(256) void softmax_k(
    const float* __restrict__ lg4, float* __restrict__ aw_out)
{
    const int b = blockIdx.x, tid = threadIdx.x;
    const float* p = lg4 + b * 2048;
    float v[8];
    #pragma unroll
    for (int i = 0; i < 8; ++i) {
        const int idx = tid + i * 256;
        v[i] = p[idx] + p[idx + 65536] + p[idx + 131072] + p[idx + 196608];
    }
    float mx = -1e30f;
    #pragma unroll
    for (int i = 0; i < 8; ++i) mx = fmaxf(mx, v[i]);
    #pragma unroll
    for (int off = 32; off >= 1; off >>= 1) mx = fmaxf(mx, __shfl_xor(mx, off, 64));
    __shared__ float redm[4], reds[4];
    const int wv = tid >> 6, ln = tid & 63;
    if (ln == 0) redm[wv] = mx;
    __syncthreads();
    mx = fmaxf(fmaxf(redm[0], redm[1]), fmaxf(redm[2], redm[3]));
    float s = 0.f;
    #pragma unroll
    for (int i = 0; i < 8; ++i) { v[i] = __expf(v[i] - mx); s += v[i]; }
    #pragma unroll
    for (int off = 32; off >= 1; off >>= 1) s += __shfl_xor(s, off, 64);
    if (ln == 0) reds[wv] = s;
    __syncthreads();
    s = reds[0] + reds[1] + reds[2] + reds[3];
    const float inv = 1.0f / s;
    #pragma unroll
    for (int i = 0; i < 8; ++i)
        aw_out[b * 2048 + tid + i * 256] = v[i] * inv;
}

// ------------------------------------------------------- context reduction
// grid 1024 = 32 b x 32 t-chunks(64); thread: float4 over d, 32 t's
__global__ __launch_bounds__(256) void context_k(
    const float* __restrict__ feats, const float* __restrict__ aw,
    float* __restrict__ ctx)
{
    const int b  = blockIdx.x >> 5;
    const int t0 = (blockIdx.x & 31) * 64 + (threadIdx.x >> 7) * 32;
    const int d4 = (threadIdx.x & 127) * 4;
    const float* fp = feats + (size_t)(b * 2048 + t0) * 512 + d4;
    const float* wp = aw + b * 2048 + t0;
    f32x4 a = (f32x4){0.f, 0.f, 0.f, 0.f};
    #pragma unroll 4
    for (int tt = 0; tt < 32; ++tt) {
        const float w = wp[tt];
        const f32x4 f = *(const f32x4*)(fp + (size_t)tt * 512);
        a.x += w * f.x; a.y += w * f.y; a.z += w * f.z; a.w += w * f.w;
    }
    atomicAdd(&ctx[b * 512 + d4],     a.x);
    atomicAdd(&ctx[b * 512 + d4 + 1], a.y);
    atomicAdd(&ctx[b * 512 + d4 + 2], a.z);
    atomicAdd(&ctx[b * 512 + d4 + 3], a.w);
}

__global__ __launch_bounds__(256) void ctx_out_k(
    const float* __restrict__ ctx, float* __restrict__ out)
{
    const int i = blockIdx.x * 256 + threadIdx.x;
    out[i] = ctx[i];
}

// ---------------------------------------------------------------- launch
extern "C" void kernel_launch(void* const* d_in, const int* in_sizes, int n_in,
                              void* d_out, int out_size, void* d_ws, size_t ws_size,
                              hipStream_t stream)
{
    const float* feats  = (const float*)d_in[0];
    const float* hidden = (const float*)d_in[1];
    const float* Wk     = (const float*)d_in[2];
    const float* Wb     = (const float*)d_in[3];
    const float* Uk     = (const float*)d_in[4];
    const float* Ub     = (const float*)d_in[5];
    const float* Vk     = (const float*)d_in[6];
    // d_in[7] = Vb: constant logit shift, cancels in softmax.

    float* out       = (float*)d_out;
    float* ctx_out_p = out;               // [32*512]  fp32
    float* aw_out_p  = out + 16384;       // [32*2048] fp32

    char* ws = (char*)d_ws;
    float*    uh  = (float*)ws;                      // 64 KB
    ushort_t* WkT = (ushort_t*)(ws + 65536);         // 512 KB
    float*    lg4 = (float*)(ws + 589824);           // 1 MB (4 partial planes)
    float*    ctx = (float*)(ws + 1638400);          // 64 KB
    ushort_t* fbf = (ushort_t*)(ws + (2u << 20));    // 64 MB (big path)

    const bool bigws = ws_size >= ((2ull << 20) + (64ull << 20));

    hipMemsetAsync(ctx, 0, 65536, stream);
    prep_uh  <<<256, 256, 0, stream>>>(hidden, Uk, Ub, Wb, uh);
    prep_wkt <<<256, 256, 0, stream>>>(Wk, WkT);
    if (bigws) {
        convert_feats<<<16384, 256, 0, stream>>>(feats, fbf);
        attn_gemm<false><<<2048, 256, 0, stream>>>(feats, fbf, WkT, uh, Vk, lg4);
    } else {
        attn_gemm<true><<<2048, 256, 0, stream>>>(feats, (const ushort_t*)nullptr,
                                                  WkT, uh, Vk, lg4);
    }
    softmax_k<<<32,   256, 0, stream>>>(lg4, aw_out_p);
    context_k<<<1024, 256, 0, stream>>>(feats, aw_out_p, ctx);
    ctx_out_k<<<64,   256, 0, stream>>>(ctx, ctx_out_p);
}

// Round 5
// 287.488 us; speedup vs baseline: 1.1438x; 1.0879x over previous
//
#include <hip/hip_runtime.h>
#include <stdint.h>

// Bahdanau additive attention, MI355X / gfx950.
// Inputs fp32, outputs fp32 (ctx[32*512] ++ aw[32*2048]).
// B=32, T=2048, D=512, U=512.  M = B*T = 65536.
//
// R5: GEMM __launch_bounds__(256,4) (4 blocks/CU); XCD sibling swizzle
//     (nc = blockIdx bits[9:8] so A-tile siblings share an XCD L2);
//     context reads bf16 feats + atomics straight into d_out;
//     prep_uh+prep_wkt fused. 5 dispatches + 1 memset.

typedef unsigned short ushort_t;
typedef __attribute__((ext_vector_type(8))) short short8;
typedef __attribute__((ext_vector_type(4))) float f32x4;
typedef __attribute__((ext_vector_type(2))) float float2v;
typedef __attribute__((ext_vector_type(2))) __bf16 bf162v;

#define GLOBAL_AS __attribute__((address_space(1)))
#define LDS_AS    __attribute__((address_space(3)))

__device__ __forceinline__ ushort_t f2bf(float f) {
    uint32_t u = __builtin_bit_cast(uint32_t, f);
    u = (u + 0x7fffu + ((u >> 16) & 1u)) >> 16;   // RNE
    return (ushort_t)u;
}
__device__ __forceinline__ float bf2f(ushort_t h) {
    uint32_t u = ((uint32_t)h) << 16;
    return __builtin_bit_cast(float, u);
}
__device__ __forceinline__ uint32_t pkbf(float a, float b) {
    bf162v r = __builtin_convertvector((float2v){a, b}, bf162v);
    return __builtin_bit_cast(uint32_t, r);
}

// ------------------------------------------------- fp32 -> bf16 features copy
__global__ __launch_bounds__(256) void convert_feats(
    const float* __restrict__ f, ushort_t* __restrict__ o)
{
    const size_t i = ((size_t)blockIdx.x * 256 + threadIdx.x) * 8;
    f32x4 a = *(const f32x4*)(f + i);
    f32x4 b = *(const f32x4*)(f + i + 4);
    union { short8 s; uint32_t u[4]; } r;
    r.u[0] = pkbf(a.x, a.y); r.u[1] = pkbf(a.z, a.w);
    r.u[2] = pkbf(b.x, b.y); r.u[3] = pkbf(b.z, b.w);
    *(short8*)(o + i) = r.s;
}

// ---------------------------------------- fused prep: uh GEMV + Wk transpose
// grid 512: blocks [0,256) -> uh; [256,512) -> WkT
__global__ __launch_bounds__(256) void prep_fused(
    const float* __restrict__ hidden, const float* __restrict__ Uk,
    const float* __restrict__ Ub, const float* __restrict__ Wb,
    const float* __restrict__ Wk,
    float* __restrict__ uh, ushort_t* __restrict__ WkT)
{
    if (blockIdx.x < 256) {
        // uh[b][u] = hidden[b]·Uk[:,u] + Ub[u] + Wb[u]
        const int b  = blockIdx.x >> 3;
        const int u  = (blockIdx.x & 7) * 64 + (threadIdx.x & 63);
        const int k0 = (threadIdx.x >> 6) * 128;
        const float* hr = hidden + b * 512;
        float acc = 0.f;
        #pragma unroll 8
        for (int k = k0; k < k0 + 128; ++k)
            acc += hr[k] * Uk[k * 512 + u];
        __shared__ float red[256];
        red[threadIdx.x] = acc;
        __syncthreads();
        if (threadIdx.x < 64) {
            const int ul = threadIdx.x;
            uh[b * 512 + u] = red[ul] + red[ul + 64] + red[ul + 128] + red[ul + 192]
                            + Ub[u] + Wb[u];
        }
    } else {
        // WkT[u][d] = bf16(Wk[d][u]) via 32x32 LDS tile
        __shared__ float t[32][33];
        const int blk = blockIdx.x - 256;
        const int ti = blk >> 4;          // d-tile
        const int tj = blk & 15;          // u-tile
        const int tx = threadIdx.x & 31;
        const int ty = threadIdx.x >> 5;  // 0..7
        #pragma unroll
        for (int q = 0; q < 4; ++q) {
            const int r = ty * 4 + q;
            t[r][tx] = Wk[(ti * 32 + r) * 512 + tj * 32 + tx];
        }
        __syncthreads();
        #pragma unroll
        for (int q = 0; q < 4; ++q) {
            const int r = ty * 4 + q;
            WkT[(tj * 32 + r) * 512 + ti * 32 + tx] = f2bf(t[tx][r]);
        }
    }
}

// ------------------------------------------------ fused GEMM+tanh+Vk-dot
// grid 2048; sibling swizzle: nc = blockIdx[9:8], mblk = blockIdx[7:0]|[10]<<8
// so the 4 blocks sharing one A-tile land on the same XCD (Δidx=256 ≡ 0 mod 8).
// __launch_bounds__(256,4): cap VGPR at 128 -> 4 blocks/CU.
template<bool CONV>
__global__ __launch_bounds__(256, 4) void attn_gemm(
    const float* __restrict__ afp, const ushort_t* __restrict__ abf,
    const ushort_t* __restrict__ WkT, const float* __restrict__ uh,
    const float* __restrict__ Vk, float* __restrict__ lg4)
{
    __shared__ __align__(16) short As[128 * 32];
    __shared__ __align__(16) short Bs[128 * 32];
    __shared__ float uh_s[128];
    __shared__ float vk_s[128];
    __shared__ float lpart[2][128];

    const int tid  = threadIdx.x;
    const int lane = tid & 63;
    const int quad = lane >> 4;
    const int lc   = lane & 15;
    const int wave = tid >> 6;
    const int wm   = wave >> 1;
    const int wn   = wave & 1;
    const int nc   = (blockIdx.x >> 8) & 3;
    const int mblk = (blockIdx.x & 255) | ((blockIdx.x >> 10) << 8);
    const int m0   = mblk * 128;
    const int bidx = m0 >> 11;       // batch index (uniform per block)

    if (tid < 128) {
        uh_s[tid] = uh[bidx * 512 + nc * 128 + tid];
        vk_s[tid] = Vk[nc * 128 + tid];
    }

    f32x4 acc[4][4];
    #pragma unroll
    for (int tm = 0; tm < 4; ++tm)
        #pragma unroll
        for (int tn = 0; tn < 4; ++tn)
            acc[tm][tn] = (f32x4){0.f, 0.f, 0.f, 0.f};

    for (int ks = 0; ks < 16; ++ks) {   // K = 512, BK = 32
        const int k0 = ks * 32;
        __syncthreads();
        {   // B tile (bf16 WkT), async 16B direct-to-LDS
            const int rowB = tid >> 2;
            const int kqB  = (tid & 3) * 8;
            #pragma unroll
            for (int rnd = 0; rnd < 2; ++rnd) {
                const int li  = rnd * 256 + tid;
                const int row = rnd * 64 + rowB;
                const ushort_t* gb = WkT + (size_t)(nc * 128 + row) * 512 + k0 + kqB;
                __builtin_amdgcn_global_load_lds(
                    (const GLOBAL_AS void*)gb, (LDS_AS void*)(Bs + li * 8), 16, 0, 0);
            }
        }
        if constexpr (CONV) {   // A tile: fp32 -> bf16 via VGPR (fallback)
            const int row = tid >> 1;
            const int k16 = (tid & 1) * 16;
            const float* ga = afp + (size_t)(m0 + row) * 512 + k0 + k16;
            f32x4 a0 = *(const f32x4*)(ga);
            f32x4 a1 = *(const f32x4*)(ga + 4);
            f32x4 a2 = *(const f32x4*)(ga + 8);
            f32x4 a3 = *(const f32x4*)(ga + 12);
            union { short8 s; uint32_t u[4]; } r0, r1;
            r0.u[0] = pkbf(a0.x, a0.y); r0.u[1] = pkbf(a0.z, a0.w);
            r0.u[2] = pkbf(a1.x, a1.y); r0.u[3] = pkbf(a1.z, a1.w);
            r1.u[0] = pkbf(a2.x, a2.y); r1.u[1] = pkbf(a2.z, a2.w);
            r1.u[2] = pkbf(a3.x, a3.y); r1.u[3] = pkbf(a3.z, a3.w);
            *(short8*)(As + row * 32 + k16)     = r0.s;
            *(short8*)(As + row * 32 + k16 + 8) = r1.s;
        } else {                // A tile: pre-converted bf16, async
            const int rowA = tid >> 2;
            const int kqA  = (tid & 3) * 8;
            #pragma unroll
            for (int rnd = 0; rnd < 2; ++rnd) {
                const int li  = rnd * 256 + tid;
                const int row = rnd * 64 + rowA;
                const ushort_t* ga = abf + (size_t)(m0 + row) * 512 + k0 + kqA;
                __builtin_amdgcn_global_load_lds(
                    (const GLOBAL_AS void*)ga, (LDS_AS void*)(As + li * 8), 16, 0, 0);
            }
        }
        __syncthreads();

        short8 af[4], bfr[4];
        #pragma unroll
        for (int t4 = 0; t4 < 4; ++t4) {
            af[t4]  = *(const short8*)(As + (wm * 64 + t4 * 16 + lc) * 32 + quad * 8);
            bfr[t4] = *(const short8*)(Bs + (wn * 64 + t4 * 16 + lc) * 32 + quad * 8);
        }
        #pragma unroll
        for (int tm = 0; tm < 4; ++tm)
            #pragma unroll
            for (int tn = 0; tn < 4; ++tn)
                acc[tm][tn] = __builtin_amdgcn_mfma_f32_16x16x32_bf16(
                    af[tm], bfr[tn], acc[tm][tn], 0, 0, 0);
    }

    // epilogue: tanh(acc + uh) * Vk -> per-row partials
    // C/D layout: col = lane&15, row = quad*4 + reg   [m89-verified]
    float rp[16];
    #pragma unroll
    for (int i = 0; i < 16; ++i) rp[i] = 0.f;
    #pragma unroll
    for (int tn = 0; tn < 4; ++tn) {
        const int nl  = wn * 64 + tn * 16 + lc;
        const float uhv = uh_s[nl];
        const float vkv = vk_s[nl];
        #pragma unroll
        for (int tm = 0; tm < 4; ++tm)
            #pragma unroll
            for (int i = 0; i < 4; ++i) {
                const float x = acc[tm][tn][i] + uhv;
                const float e = __expf(2.0f * x);          // tanh = 1 - 2/(e^{2x}+1)
                rp[tm * 4 + i] += (1.0f - 2.0f / (e + 1.0f)) * vkv;
            }
    }
    #pragma unroll
    for (int i = 0; i < 16; ++i) {
        float v = rp[i];
        v += __shfl_xor(v, 1, 64);
        v += __shfl_xor(v, 2, 64);
        v += __shfl_xor(v, 4, 64);
        v += __shfl_xor(v, 8, 64);
        rp[i] = v;
    }
    if (lc == 0) {
        #pragma unroll
        for (int tm = 0; tm < 4; ++tm)
            #pragma unroll
            for (int i = 0; i < 4; ++i)
                lpart[wn][wm * 64 + tm * 16 + quad * 4 + i] = rp[tm * 4 + i];
    }
    __syncthreads();
    if (tid < 128)
        lg4[(size_t)nc * 65536 + m0 + tid] = lpart[0][tid] + lpart[1][tid];
}

// ---------------------------------------------------------------- softmax
__global__ __launch_bounds__(256) void softmax_k(
    const float* __restrict__ lg4, float* __restrict__ aw_out)
{
    const int b = blockIdx.x, tid = threadIdx.x;
    const float* p = lg4 + b * 2048;
    float v[8];
    #pragma unroll
    for (int i = 0; i < 8; ++i) {
        const int idx = tid + i * 256;
        v[i] = p[idx] + p[idx + 65536] + p[idx + 131072] + p[idx + 196608];
    }
    float mx = -1e30f;
    #pragma unroll
    for (int i = 0; i < 8; ++i) mx = fmaxf(mx, v[i]);
    #pragma unroll
    for (int off = 32; off >= 1; off >>= 1) mx = fmaxf(mx, __shfl_xor(mx, off, 64));
    __shared__ float redm[4], reds[4];
    const int wv = tid >> 6, ln = tid & 63;
    if (ln == 0) redm[wv] = mx;
    __syncthreads();
    mx = fmaxf(fmaxf(redm[0], redm[1]), fmaxf(redm[2], redm[3]));
    float s = 0.f;
    #pragma unroll
    for (int i = 0; i < 8; ++i) { v[i] = __expf(v[i] - mx); s += v[i]; }
    #pragma unroll
    for (int off = 32; off >= 1; off >>= 1) s += __shfl_xor(s, off, 64);
    if (ln == 0) reds[wv] = s;
    __syncthreads();
    s = reds[0] + reds[1] + reds[2] + reds[3];
    const float inv = 1.0f / s;
    #pragma unroll
    for (int i = 0; i < 8; ++i)
        aw_out[b * 2048 + tid + i * 256] = v[i] * inv;
}

// ------------------------------------------------------- context reduction
// grid 512 = 32 b x 16 t-chunks(128); thread: 4 bf16 d-values, 64 t's.
// BF=true reads bf16 feats (big-ws path), else fp32.
template<bool BF>
__global__ __launch_bounds__(256) void context_k(
    const ushort_t* __restrict__ fb, const float* __restrict__ ff,
    const float* __restrict__ aw, float* __restrict__ ctx_out)
{
    const int b  = blockIdx.x >> 4;
    const int t0 = (blockIdx.x & 15) * 128 + (threadIdx.x >> 7) * 64;
    const int d4 = (threadIdx.x & 127) * 4;
    const float* wp = aw + b * 2048 + t0;
    f32x4 a = (f32x4){0.f, 0.f, 0.f, 0.f};
    if constexpr (BF) {
        const ushort_t* fp = fb + (size_t)(b * 2048 + t0) * 512 + d4;
        #pragma unroll 4
        for (int tt = 0; tt < 64; ++tt) {
            const float w = wp[tt];
            union { uint2 u2; ushort_t h[4]; } r;
            r.u2 = *(const uint2*)(fp + (size_t)tt * 512);
            a.x += w * bf2f(r.h[0]); a.y += w * bf2f(r.h[1]);
            a.z += w * bf2f(r.h[2]); a.w += w * bf2f(r.h[3]);
        }
    } else {
        const float* fp = ff + (size_t)(b * 2048 + t0) * 512 + d4;
        #pragma unroll 4
        for (int tt = 0; tt < 64; ++tt) {
            const float w = wp[tt];
            const f32x4 f = *(const f32x4*)(fp + (size_t)tt * 512);
            a.x += w * f.x; a.y += w * f.y; a.z += w * f.z; a.w += w * f.w;
        }
    }
    atomicAdd(&ctx_out[b * 512 + d4],     a.x);
    atomicAdd(&ctx_out[b * 512 + d4 + 1], a.y);
    atomicAdd(&ctx_out[b * 512 + d4 + 2], a.z);
    atomicAdd(&ctx_out[b * 512 + d4 + 3], a.w);
}

// ---------------------------------------------------------------- launch
extern "C" void kernel_launch(void* const* d_in, const int* in_sizes, int n_in,
                              void* d_out, int out_size, void* d_ws, size_t ws_size,
                              hipStream_t stream)
{
    const float* feats  = (const float*)d_in[0];
    const float* hidden = (const float*)d_in[1];
    const float* Wk     = (const float*)d_in[2];
    const float* Wb     = (const float*)d_in[3];
    const float* Uk     = (const float*)d_in[4];
    const float* Ub     = (const float*)d_in[5];
    const float* Vk     = (const float*)d_in[6];
    // d_in[7] = Vb: constant logit shift, cancels in softmax.

    float* out       = (float*)d_out;
    float* ctx_out_p = out;               // [32*512]  fp32 (atomic target)
    float* aw_out_p  = out + 16384;       // [32*2048] fp32

    char* ws = (char*)d_ws;
    float*    uh  = (float*)ws;                      // 64 KB
    ushort_t* WkT = (ushort_t*)(ws + 65536);         // 512 KB
    float*    lg4 = (float*)(ws + 589824);           // 1 MB (4 partial planes)
    ushort_t* fbf = (ushort_t*)(ws + (2u << 20));    // 64 MB (big path)

    const bool bigws = ws_size >= ((2ull << 20) + (64ull << 20));

    hipMemsetAsync(ctx_out_p, 0, 65536, stream);     // zero ctx in d_out
    prep_fused<<<512, 256, 0, stream>>>(hidden, Uk, Ub, Wb, Wk, uh, WkT);
    if (bigws) {
        convert_feats<<<16384, 256, 0, stream>>>(feats, fbf);
        attn_gemm<false><<<2048, 256, 0, stream>>>(feats, fbf, WkT, uh, Vk, lg4);
        softmax_k<<<32,  256, 0, stream>>>(lg4, aw_out_p);
        context_k<true><<<512, 256, 0, stream>>>(fbf, feats, aw_out_p, ctx_out_p);
    } else {
        attn_gemm<true><<<2048, 256, 0, stream>>>(feats, (const ushort_t*)nullptr,
                                                  WkT, uh, Vk, lg4);
        softmax_k<<<32,  256, 0, stream>>>(lg4, aw_out_p);
        context_k<false><<<512, 256, 0, stream>>>((const ushort_t*)nullptr, feats,
                                                  aw_out_p, ctx_out_p);
    }
}

// Round 6
// 284.919 us; speedup vs baseline: 1.1541x; 1.0090x over previous
//
#include <hip/hip_runtime.h>
#include <stdint.h>

// Bahdanau additive attention, MI355X / gfx950.
// Inputs fp32, outputs fp32 (ctx[32*512] ++ aw[32*2048]).
// B=32, T=2048, D=512, U=512.  M = B*T = 65536.
//
// R6: GEMM tile 256x128 (512 thr, 8 waves 4x2) — halves block count,
//     barrier drains, B L2 traffic; doubles prologue/epilogue amortization.
//     convert+prep+ctx-zero fused into one dispatch. 4 dispatches total.

typedef unsigned short ushort_t;
typedef __attribute__((ext_vector_type(8))) short short8;
typedef __attribute__((ext_vector_type(4))) float f32x4;
typedef __attribute__((ext_vector_type(2))) float float2v;
typedef __attribute__((ext_vector_type(2))) __bf16 bf162v;

#define GLOBAL_AS __attribute__((address_space(1)))
#define LDS_AS    __attribute__((address_space(3)))

__device__ __forceinline__ ushort_t f2bf(float f) {
    uint32_t u = __builtin_bit_cast(uint32_t, f);
    u = (u + 0x7fffu + ((u >> 16) & 1u)) >> 16;   // RNE
    return (ushort_t)u;
}
__device__ __forceinline__ float bf2f(ushort_t h) {
    uint32_t u = ((uint32_t)h) << 16;
    return __builtin_bit_cast(float, u);
}
__device__ __forceinline__ uint32_t pkbf(float a, float b) {
    bf162v r = __builtin_convertvector((float2v){a, b}, bf162v);
    return __builtin_bit_cast(uint32_t, r);
}

// --------------------------- fused: feats fp32->bf16 + uh GEMV + WkT + ctx=0
// grid 16960 = 16384 convert | 256 uh | 256 WkT | 64 ctx-zero
__global__ __launch_bounds__(256) void prep_all(
    const float* __restrict__ feats, ushort_t* __restrict__ fbf,
    const float* __restrict__ hidden, const float* __restrict__ Uk,
    const float* __restrict__ Ub, const float* __restrict__ Wb,
    const float* __restrict__ Wk,
    float* __restrict__ uh, ushort_t* __restrict__ WkT,
    float* __restrict__ ctx_out)
{
    if (blockIdx.x < 16384) {
        const size_t i = ((size_t)blockIdx.x * 256 + threadIdx.x) * 8;
        f32x4 a = *(const f32x4*)(feats + i);
        f32x4 b = *(const f32x4*)(feats + i + 4);
        union { short8 s; uint32_t u[4]; } r;
        r.u[0] = pkbf(a.x, a.y); r.u[1] = pkbf(a.z, a.w);
        r.u[2] = pkbf(b.x, b.y); r.u[3] = pkbf(b.z, b.w);
        *(short8*)(fbf + i) = r.s;
        return;
    }
    const int pb = blockIdx.x - 16384;
    if (pb < 256) {
        // uh[b][u] = hidden[b]·Uk[:,u] + Ub[u] + Wb[u]
        const int b  = pb >> 3;
        const int u  = (pb & 7) * 64 + (threadIdx.x & 63);
        const int k0 = (threadIdx.x >> 6) * 128;
        const float* hr = hidden + b * 512;
        float acc = 0.f;
        #pragma unroll 8
        for (int k = k0; k < k0 + 128; ++k)
            acc += hr[k] * Uk[k * 512 + u];
        __shared__ float red[256];
        red[threadIdx.x] = acc;
        __syncthreads();
        if (threadIdx.x < 64) {
            const int ul = threadIdx.x;
            uh[b * 512 + u] = red[ul] + red[ul + 64] + red[ul + 128] + red[ul + 192]
                            + Ub[u] + Wb[u];
        }
    } else if (pb < 512) {
        // WkT[u][d] = bf16(Wk[d][u]) via 32x32 LDS tile
        __shared__ float t[32][33];
        const int blk = pb - 256;
        const int ti = blk >> 4;
        const int tj = blk & 15;
        const int tx = threadIdx.x & 31;
        const int ty = threadIdx.x >> 5;
        #pragma unroll
        for (int q = 0; q < 4; ++q) {
            const int r = ty * 4 + q;
            t[r][tx] = Wk[(ti * 32 + r) * 512 + tj * 32 + tx];
        }
        __syncthreads();
        #pragma unroll
        for (int q = 0; q < 4; ++q) {
            const int r = ty * 4 + q;
            WkT[(tj * 32 + r) * 512 + ti * 32 + tx] = f2bf(t[tx][r]);
        }
    } else {
        ctx_out[(pb - 512) * 256 + threadIdx.x] = 0.f;   // zero ctx in d_out
    }
}

// ------------------------------------------------ fused GEMM+tanh+Vk-dot
// grid 1024 = 256 M-tiles(256 rows) x 4 N-chunks; 512 threads, 8 waves 4x2.
// Sibling swizzle: nc = bits[8:7] so the 4 blocks sharing one A-tile are
// Δidx=128 ≡ 0 mod 8 apart (same XCD L2).
template<bool CONV>
__global__ __launch_bounds__(512, 4) void attn_gemm(
    const float* __restrict__ afp, const ushort_t* __restrict__ abf,
    const ushort_t* __restrict__ WkT, const float* __restrict__ uh,
    const float* __restrict__ Vk, float* __restrict__ lg4)
{
    __shared__ __align__(16) short As[256 * 32];
    __shared__ __align__(16) short Bs[128 * 32];
    __shared__ float uh_s[128];
    __shared__ float vk_s[128];
    __shared__ float lpart[2][256];

    const int tid  = threadIdx.x;
    const int lane = tid & 63;
    const int quad = lane >> 4;
    const int lc   = lane & 15;
    const int wave = tid >> 6;       // 0..7
    const int wm   = wave >> 1;      // 0..3 (64-row strip)
    const int wn   = wave & 1;       // 0..1 (64-col strip)
    const int nc   = (blockIdx.x >> 7) & 3;
    const int mtile= (blockIdx.x & 127) | ((blockIdx.x >> 9) << 7);
    const int m0   = mtile * 256;
    const int bidx = m0 >> 11;       // batch index (256 | 2048 -> uniform)

    if (tid < 128) {
        uh_s[tid] = uh[bidx * 512 + nc * 128 + tid];
        vk_s[tid] = Vk[nc * 128 + tid];
    }

    f32x4 acc[4][4];
    #pragma unroll
    for (int tm = 0; tm < 4; ++tm)
        #pragma unroll
        for (int tn = 0; tn < 4; ++tn)
            acc[tm][tn] = (f32x4){0.f, 0.f, 0.f, 0.f};

    for (int ks = 0; ks < 16; ++ks) {   // K = 512, BK = 32
        const int k0 = ks * 32;
        __syncthreads();
        {   // B tile 128x32 (bf16 WkT): 1 round of 512 async 16B
            const int row = tid >> 2;
            const int kq  = (tid & 3) * 8;
            const ushort_t* gb = WkT + (size_t)(nc * 128 + row) * 512 + k0 + kq;
            __builtin_amdgcn_global_load_lds(
                (const GLOBAL_AS void*)gb, (LDS_AS void*)(Bs + tid * 8), 16, 0, 0);
        }
        if constexpr (CONV) {   // A tile 256x32: fp32 -> bf16 via VGPR
            const int row = tid >> 1;
            const int k16 = (tid & 1) * 16;
            const float* ga = afp + (size_t)(m0 + row) * 512 + k0 + k16;
            f32x4 a0 = *(const f32x4*)(ga);
            f32x4 a1 = *(const f32x4*)(ga + 4);
            f32x4 a2 = *(const f32x4*)(ga + 8);
            f32x4 a3 = *(const f32x4*)(ga + 12);
            union { short8 s; uint32_t u[4]; } r0, r1;
            r0.u[0] = pkbf(a0.x, a0.y); r0.u[1] = pkbf(a0.z, a0.w);
            r0.u[2] = pkbf(a1.x, a1.y); r0.u[3] = pkbf(a1.z, a1.w);
            r1.u[0] = pkbf(a2.x, a2.y); r1.u[1] = pkbf(a2.z, a2.w);
            r1.u[2] = pkbf(a3.x, a3.y); r1.u[3] = pkbf(a3.z, a3.w);
            *(short8*)(As + row * 32 + k16)     = r0.s;
            *(short8*)(As + row * 32 + k16 + 8) = r1.s;
        } else {                // A tile 256x32: 2 rounds of 512 async 16B
            #pragma unroll
            for (int rnd = 0; rnd < 2; ++rnd) {
                const int li  = rnd * 512 + tid;
                const int row = li >> 2;
                const int kq  = (li & 3) * 8;
                const ushort_t* ga = abf + (size_t)(m0 + row) * 512 + k0 + kq;
                __builtin_amdgcn_global_load_lds(
                    (const GLOBAL_AS void*)ga, (LDS_AS void*)(As + li * 8), 16, 0, 0);
            }
        }
        __syncthreads();

        short8 af[4], bfr[4];
        #pragma unroll
        for (int t4 = 0; t4 < 4; ++t4) {
            af[t4]  = *(const short8*)(As + (wm * 64 + t4 * 16 + lc) * 32 + quad * 8);
            bfr[t4] = *(const short8*)(Bs + (wn * 64 + t4 * 16 + lc) * 32 + quad * 8);
        }
        #pragma unroll
        for (int tm = 0; tm < 4; ++tm)
            #pragma unroll
            for (int tn = 0; tn < 4; ++tn)
                acc[tm][tn] = __builtin_amdgcn_mfma_f32_16x16x32_bf16(
                    af[tm], bfr[tn], acc[tm][tn], 0, 0, 0);
    }

    // epilogue: tanh(acc + uh) * Vk -> per-row partials
    // C/D layout: col = lane&15, row = quad*4 + reg   [m89-verified]
    float rp[16];
    #pragma unroll
    for (int i = 0; i < 16; ++i) rp[i] = 0.f;
    #pragma unroll
    for (int tn = 0; tn < 4; ++tn) {
        const int nl  = wn * 64 + tn * 16 + lc;
        const float uhv = uh_s[nl];
        const float vkv = vk_s[nl];
        #pragma unroll
        for (int tm = 0; tm < 4; ++tm)
            #pragma unroll
            for (int i = 0; i < 4; ++i) {
                const float x = acc[tm][tn][i] + uhv;
                const float e = __expf(2.0f * x);          // tanh = 1 - 2/(e^{2x}+1)
                rp[tm * 4 + i] += (1.0f - 2.0f / (e + 1.0f)) * vkv;
            }
    }
    #pragma unroll
    for (int i = 0; i < 16; ++i) {
        float v = rp[i];
        v += __shfl_xor(v, 1, 64);
        v += __shfl_xor(v, 2, 64);
        v += __shfl_xor(v, 4, 64);
        v += __shfl_xor(v, 8, 64);
        rp[i] = v;
    }
    if (lc == 0) {
        #pragma unroll
        for (int tm = 0; tm < 4; ++tm)
            #pragma unroll
            for (int i = 0; i < 4; ++i)
                lpart[wn][wm * 64 + tm * 16 + quad * 4 + i] = rp[tm * 4 + i];
    }
    __syncthreads();
    if (tid < 256)
        lg4[(size_t)nc * 65536 + m0 + tid] = lpart[0][tid] + lpart[1][tid];
}

// ---------------------------------------------------------------- softmax
__global__ __launch_bounds__(256) void softmax_k(
    const float* __restrict__ lg4, float* __restrict__ aw_out)
{
    const int b = blockIdx.x, tid = threadIdx.x;
    const float* p = lg4 + b * 2048;
    float v[8];
    #pragma unroll
    for (int i = 0; i < 8; ++i) {
        const int idx = tid + i * 256;
        v[i] = p[idx] + p[idx + 65536] + p[idx + 131072] + p[idx + 196608];
    }
    float mx = -1e30f;
    #pragma unroll
    for (int i = 0; i < 8; ++i) mx = fmaxf(mx, v[i]);
    #pragma unroll
    for (int off = 32; off >= 1; off >>= 1) mx = fmaxf(mx, __shfl_xor(mx, off, 64));
    __shared__ float redm[4], reds[4];
    const int wv = tid >> 6, ln = tid & 63;
    if (ln == 0) redm[wv] = mx;
    __syncthreads();
    mx = fmaxf(fmaxf(redm[0], redm[1]), fmaxf(redm[2], redm[3]));
    float s = 0.f;
    #pragma unroll
    for (int i = 0; i < 8; ++i) { v[i] = __expf(v[i] - mx); s += v[i]; }
    #pragma unroll
    for (int off = 32; off >= 1; off >>= 1) s += __shfl_xor(s, off, 64);
    if (ln == 0) reds[wv] = s;
    __syncthreads();
    s = reds[0] + reds[1] + reds[2] + reds[3];
    const float inv = 1.0f / s;
    #pragma unroll
    for (int i = 0; i < 8; ++i)
        aw_out[b * 2048 + tid + i * 256] = v[i] * inv;
}

// ------------------------------------------------------- context reduction
// grid 512 = 32 b x 16 t-chunks(128); thread: 4 bf16 d-values, 64 t's.
template<bool BF>
__global__ __launch_bounds__(256) void context_k(
    const ushort_t* __restrict__ fb, const float* __restrict__ ff,
    const float* __restrict__ aw, float* __restrict__ ctx_out)
{
    const int b  = blockIdx.x >> 4;
    const int t0 = (blockIdx.x & 15) * 128 + (threadIdx.x >> 7) * 64;
    const int d4 = (threadIdx.x & 127) * 4;
    const float* wp = aw + b * 2048 + t0;
    f32x4 a = (f32x4){0.f, 0.f, 0.f, 0.f};
    if constexpr (BF) {
        const ushort_t* fp = fb + (size_t)(b * 2048 + t0) * 512 + d4;
        #pragma unroll 4
        for (int tt = 0; tt < 64; ++tt) {
            const float w = wp[tt];
            union { uint2 u2; ushort_t h[4]; } r;
            r.u2 = *(const uint2*)(fp + (size_t)tt * 512);
            a.x += w * bf2f(r.h[0]); a.y += w * bf2f(r.h[1]);
            a.z += w * bf2f(r.h[2]); a.w += w * bf2f(r.h[3]);
        }
    } else {
        const float* fp = ff + (size_t)(b * 2048 + t0) * 512 + d4;
        #pragma unroll 4
        for (int tt = 0; tt < 64; ++tt) {
            const float w = wp[tt];
            const f32x4 f = *(const f32x4*)(fp + (size_t)tt * 512);
            a.x += w * f.x; a.y += w * f.y; a.z += w * f.z; a.w += w * f.w;
        }
    }
    atomicAdd(&ctx_out[b * 512 + d4],     a.x);
    atomicAdd(&ctx_out[b * 512 + d4 + 1], a.y);
    atomicAdd(&ctx_out[b * 512 + d4 + 2], a.z);
    atomicAdd(&ctx_out[b * 512 + d4 + 3], a.w);
}

// ---------------------------------------------------------------- launch
extern "C" void kernel_launch(void* const* d_in, const int* in_sizes, int n_in,
                              void* d_out, int out_size, void* d_ws, size_t ws_size,
                              hipStream_t stream)
{
    const float* feats  = (const float*)d_in[0];
    const float* hidden = (const float*)d_in[1];
    const float* Wk     = (const float*)d_in[2];
    const float* Wb     = (const float*)d_in[3];
    const float* Uk     = (const float*)d_in[4];
    const float* Ub     = (const float*)d_in[5];
    const float* Vk     = (const float*)d_in[6];
    // d_in[7] = Vb: constant logit shift, cancels in softmax.

    float* out       = (float*)d_out;
    float* ctx_out_p = out;               // [32*512]  fp32 (atomic target)
    float* aw_out_p  = out + 16384;       // [32*2048] fp32

    char* ws = (char*)d_ws;
    float*    uh  = (float*)ws;                      // 64 KB
    ushort_t* WkT = (ushort_t*)(ws + 65536);         // 512 KB
    float*    lg4 = (float*)(ws + 589824);           // 1 MB (4 partial planes)
    ushort_t* fbf = (ushort_t*)(ws + (2u << 20));    // 64 MB (big path)

    const bool bigws = ws_size >= ((2ull << 20) + (64ull << 20));

    if (bigws) {
        prep_all<<<16960, 256, 0, stream>>>(feats, fbf, hidden, Uk, Ub, Wb, Wk,
                                            uh, WkT, ctx_out_p);
        attn_gemm<false><<<1024, 512, 0, stream>>>(feats, fbf, WkT, uh, Vk, lg4);
        softmax_k<<<32,  256, 0, stream>>>(lg4, aw_out_p);
        context_k<true><<<512, 256, 0, stream>>>(fbf, feats, aw_out_p, ctx_out_p);
    } else {
        prep_all<<<16960, 256, 0, stream>>>(feats, (ushort_t*)uh /*unused dummy*/,
                                            hidden, Uk, Ub, Wb, Wk, uh, WkT,
                                            ctx_out_p);
        attn_gemm<true><<<1024, 512, 0, stream>>>(feats, (const ushort_t*)nullptr,
                                                  WkT, uh, Vk, lg4);
        softmax_k<<<32,  256, 0, stream>>>(lg4, aw_out_p);
        context_k<false><<<512, 256, 0, stream>>>((const ushort_t*)nullptr, feats,
                                                  aw_out_p, ctx_out_p);
    }
}

// Round 7
// 262.280 us; speedup vs baseline: 1.2537x; 1.0863x over previous
//
#include <hip/hip_runtime.h>
#include <stdint.h>

// Bahdanau additive attention, MI355X / gfx950.
// Inputs fp32, outputs fp32 (ctx[32*512] ++ aw[32*2048]).
// B=32, T=2048, D=512, U=512.  M = B*T = 65536.
//
// R7: single-pass GEMM — 512 blocks x 1024 thr (16 waves, 2Mx8N of 64x64),
//     M-tile 128, all N=512 in acc (64 f32/thread). A read once as fp32,
//     converted in-kernel (convert kernel deleted). B (WkT, L2-resident)
//     double-buffered in LDS with real software pipelining (issue loads ->
//     MFMA -> convert/ds_write -> barrier). A-LDS padded to 40 shorts.
//     4 dispatches: prep(uh+WkT+ctx0), gemm, softmax, context(fp32).

typedef unsigned short ushort_t;
typedef __attribute__((ext_vector_type(8))) short short8;
typedef __attribute__((ext_vector_type(4))) float f32x4;
typedef __attribute__((ext_vector_type(2))) float float2v;
typedef __attribute__((ext_vector_type(2))) __bf16 bf162v;

#define GLOBAL_AS __attribute__((address_space(1)))
#define LDS_AS    __attribute__((address_space(3)))

__device__ __forceinline__ ushort_t f2bf(float f) {
    uint32_t u = __builtin_bit_cast(uint32_t, f);
    u = (u + 0x7fffu + ((u >> 16) & 1u)) >> 16;   // RNE
    return (ushort_t)u;
}
__device__ __forceinline__ uint32_t pkbf(float a, float b) {
    bf162v r = __builtin_convertvector((float2v){a, b}, bf162v);
    return __builtin_bit_cast(uint32_t, r);
}

// --------------------------- fused prep: uh GEMV + WkT transpose + ctx zero
// grid 576 = 256 uh | 256 WkT | 64 ctx-zero
__global__ __launch_bounds__(256) void prep_all(
    const float* __restrict__ hidden, const float* __restrict__ Uk,
    const float* __restrict__ Ub, const float* __restrict__ Wb,
    const float* __restrict__ Wk,
    float* __restrict__ uh, ushort_t* __restrict__ WkT,
    float* __restrict__ ctx_out)
{
    const int pb = blockIdx.x;
    if (pb < 256) {
        // uh[b][u] = hidden[b]·Uk[:,u] + Ub[u] + Wb[u]
        const int b  = pb >> 3;
        const int u  = (pb & 7) * 64 + (threadIdx.x & 63);
        const int k0 = (threadIdx.x >> 6) * 128;
        const float* hr = hidden + b * 512;
        float acc = 0.f;
        #pragma unroll 8
        for (int k = k0; k < k0 + 128; ++k)
            acc += hr[k] * Uk[k * 512 + u];
        __shared__ float red[256];
        red[threadIdx.x] = acc;
        __syncthreads();
        if (threadIdx.x < 64) {
            const int ul = threadIdx.x;
            uh[b * 512 + u] = red[ul] + red[ul + 64] + red[ul + 128] + red[ul + 192]
                            + Ub[u] + Wb[u];
        }
    } else if (pb < 512) {
        // WkT[u][d] = bf16(Wk[d][u]) via 32x32 LDS tile
        __shared__ float t[32][33];
        const int blk = pb - 256;
        const int ti = blk >> 4;
        const int tj = blk & 15;
        const int tx = threadIdx.x & 31;
        const int ty = threadIdx.x >> 5;
        #pragma unroll
        for (int q = 0; q < 4; ++q) {
            const int r = ty * 4 + q;
            t[r][tx] = Wk[(ti * 32 + r) * 512 + tj * 32 + tx];
        }
        __syncthreads();
        #pragma unroll
        for (int q = 0; q < 4; ++q) {
            const int r = ty * 4 + q;
            WkT[(tj * 32 + r) * 512 + ti * 32 + tx] = f2bf(t[tx][r]);
        }
    } else {
        ctx_out[(pb - 512) * 256 + threadIdx.x] = 0.f;   // zero ctx in d_out
    }
}

// ------------------------------------------------ fused GEMM+tanh+Vk-dot
// grid 512 M-tiles of 128 rows; 1024 threads = 16 waves (2M x 8N, 64x64 each).
// All N=512 held in acc. A fp32->bf16 in-kernel; B double-buffered.
#define APAD 40   // A row stride in shorts (breaks bank aliasing)
__global__ __launch_bounds__(1024, 4) void attn_gemm(
    const float* __restrict__ feats, const ushort_t* __restrict__ WkT,
    const float* __restrict__ uh, const float* __restrict__ Vk,
    float* __restrict__ lg)
{
    __shared__ __align__(16) short As[2][128 * APAD];
    __shared__ __align__(16) short Bs[2][512 * 32];
    __shared__ float uh_s[512];
    __shared__ float vk_s[512];
    __shared__ float lpart[8][128];

    const int tid  = threadIdx.x;
    const int lane = tid & 63;
    const int quad = lane >> 4;
    const int lc   = lane & 15;
    const int wave = tid >> 6;       // 0..15
    const int wm   = wave >> 3;      // 0..1  (64-row strip)
    const int wn   = wave & 7;       // 0..7  (64-col strip)
    const int m0   = blockIdx.x * 128;
    const int bidx = m0 >> 11;       // batch index (uniform per block)

    if (tid < 512) {
        uh_s[tid] = uh[bidx * 512 + tid];
        vk_s[tid] = Vk[tid];
    }

    const int rowA = tid >> 3;          // 0..127
    const int kA   = (tid & 3) * 8;     // unused
    const int kAo  = (tid & 7) * 4;     // fp32 k-offset 0..28
    const int rowB = tid >> 2;          // staging helper (with li)

    f32x4 acc[4][4];
    #pragma unroll
    for (int tm = 0; tm < 4; ++tm)
        #pragma unroll
        for (int tn = 0; tn < 4; ++tn)
            acc[tm][tn] = (f32x4){0.f, 0.f, 0.f, 0.f};

    // ---- prologue: stage chunk 0 into buf 0
    {
        #pragma unroll
        for (int rnd = 0; rnd < 2; ++rnd) {
            const int li = rnd * 1024 + tid;
            const int rB = li >> 2;
            const int kq = (li & 3) * 8;
            const ushort_t* gb = WkT + (size_t)rB * 512 + kq;
            __builtin_amdgcn_global_load_lds(
                (const GLOBAL_AS void*)gb, (LDS_AS void*)(Bs[0] + li * 8), 16, 0, 0);
        }
        const f32x4 av = *(const f32x4*)(feats + (size_t)(m0 + rowA) * 512 + kAo);
        uint2 w;
        w.x = pkbf(av.x, av.y);
        w.y = pkbf(av.z, av.w);
        *(uint2*)(As[0] + rowA * APAD + kAo) = w;
    }

    int buf = 0;
    for (int ks = 0; ks < 16; ++ks) {   // K = 512, BK = 32
        __syncthreads();                // staging of `buf` complete

        f32x4 a_next;
        const bool have = (ks + 1) < 16;
        if (have) {
            const int k0n = (ks + 1) * 32;
            #pragma unroll
            for (int rnd = 0; rnd < 2; ++rnd) {
                const int li = rnd * 1024 + tid;
                const int rB = li >> 2;
                const int kq = (li & 3) * 8;
                const ushort_t* gb = WkT + (size_t)rB * 512 + k0n + kq;
                __builtin_amdgcn_global_load_lds(
                    (const GLOBAL_AS void*)gb, (LDS_AS void*)(Bs[buf ^ 1] + li * 8),
                    16, 0, 0);
            }
            a_next = *(const f32x4*)(feats + (size_t)(m0 + rowA) * 512 + k0n + kAo);
        }

        // ---- compute on `buf` (hides the loads above)
        short8 af[4], bfr[4];
        #pragma unroll
        for (int t4 = 0; t4 < 4; ++t4) {
            af[t4]  = *(const short8*)(As[buf] + (wm * 64 + t4 * 16 + lc) * APAD + quad * 8);
            bfr[t4] = *(const short8*)(Bs[buf] + (wn * 64 + t4 * 16 + lc) * 32 + quad * 8);
        }
        #pragma unroll
        for (int tm = 0; tm < 4; ++tm)
            #pragma unroll
            for (int tn = 0; tn < 4; ++tn)
                acc[tm][tn] = __builtin_amdgcn_mfma_f32_16x16x32_bf16(
                    af[tm], bfr[tn], acc[tm][tn], 0, 0, 0);

        if (have) {
            uint2 w;
            w.x = pkbf(a_next.x, a_next.y);
            w.y = pkbf(a_next.z, a_next.w);
            *(uint2*)(As[buf ^ 1] + rowA * APAD + kAo) = w;
        }
        buf ^= 1;
    }
    (void)kA; (void)rowB;

    // epilogue: tanh(acc + uh) * Vk -> per-row partials
    // C/D layout: col = lane&15, row = quad*4 + reg   [m89-verified]
    float rp[16];
    #pragma unroll
    for (int i = 0; i < 16; ++i) rp[i] = 0.f;
    #pragma unroll
    for (int tn = 0; tn < 4; ++tn) {
        const int nl  = wn * 64 + tn * 16 + lc;
        const float uhv = uh_s[nl];
        const float vkv = vk_s[nl];
        #pragma unroll
        for (int tm = 0; tm < 4; ++tm)
            #pragma unroll
            for (int i = 0; i < 4; ++i) {
                const float x = acc[tm][tn][i] + uhv;
                const float e = __expf(2.0f * x);          // tanh = 1 - 2/(e^{2x}+1)
                rp[tm * 4 + i] += (1.0f - 2.0f / (e + 1.0f)) * vkv;
            }
    }
    #pragma unroll
    for (int i = 0; i < 16; ++i) {
        float v = rp[i];
        v += __shfl_xor(v, 1, 64);
        v += __shfl_xor(v, 2, 64);
        v += __shfl_xor(v, 4, 64);
        v += __shfl_xor(v, 8, 64);
        rp[i] = v;
    }
    if (lc == 0) {
        #pragma unroll
        for (int tm = 0; tm < 4; ++tm)
            #pragma unroll
            for (int i = 0; i < 4; ++i)
                lpart[wn][wm * 64 + tm * 16 + quad * 4 + i] = rp[tm * 4 + i];
    }
    __syncthreads();
    if (tid < 128) {
        float s = 0.f;
        #pragma unroll
        for (int j = 0; j < 8; ++j) s += lpart[j][tid];
        lg[m0 + tid] = s;
    }
}

// ---------------------------------------------------------------- softmax
__global__ __launch_bounds__(256) void softmax_k(
    const float* __restrict__ lg, float* __restrict__ aw_out)
{
    const int b = blockIdx.x, tid = threadIdx.x;
    const float* p = lg + b * 2048;
    float v[8];
    #pragma unroll
    for (int i = 0; i < 8; ++i) v[i] = p[tid + i * 256];
    float mx = -1e30f;
    #pragma unroll
    for (int i = 0; i < 8; ++i) mx = fmaxf(mx, v[i]);
    #pragma unroll
    for (int off = 32; off >= 1; off >>= 1) mx = fmaxf(mx, __shfl_xor(mx, off, 64));
    __shared__ float redm[4], reds[4];
    const int wv = tid >> 6, ln = tid & 63;
    if (ln == 0) redm[wv] = mx;
    __syncthreads();
    mx = fmaxf(fmaxf(redm[0], redm[1]), fmaxf(redm[2], redm[3]));
    float s = 0.f;
    #pragma unroll
    for (int i = 0; i < 8; ++i) { v[i] = __expf(v[i] - mx); s += v[i]; }
    #pragma unroll
    for (int off = 32; off >= 1; off >>= 1) s += __shfl_xor(s, off, 64);
    if (ln == 0) reds[wv] = s;
    __syncthreads();
    s = reds[0] + reds[1] + reds[2] + reds[3];
    const float inv = 1.0f / s;
    #pragma unroll
    for (int i = 0; i < 8; ++i)
        aw_out[b * 2048 + tid + i * 256] = v[i] * inv;
}

// ------------------------------------------------------- context reduction
// grid 512 = 32 b x 16 t-chunks(128); thread: float4 over d, 64 t's.
__global__ __launch_bounds__(256) void context_k(
    const float* __restrict__ feats, const float* __restrict__ aw,
    float* __restrict__ ctx_out)
{
    const int b  = blockIdx.x >> 4;
    const int t0 = (blockIdx.x & 15) * 128 + (threadIdx.x >> 7) * 64;
    const int d4 = (threadIdx.x & 127) * 4;
    const float* wp = aw + b * 2048 + t0;
    const float* fp = feats + (size_t)(b * 2048 + t0) * 512 + d4;
    f32x4 a = (f32x4){0.f, 0.f, 0.f, 0.f};
    #pragma unroll 4
    for (int tt = 0; tt < 64; ++tt) {
        const float w = wp[tt];
        const f32x4 f = *(const f32x4*)(fp + (size_t)tt * 512);
        a.x += w * f.x; a.y += w * f.y; a.z += w * f.z; a.w += w * f.w;
    }
    atomicAdd(&ctx_out[b * 512 + d4],     a.x);
    atomicAdd(&ctx_out[b * 512 + d4 + 1], a.y);
    atomicAdd(&ctx_out[b * 512 + d4 + 2], a.z);
    atomicAdd(&ctx_out[b * 512 + d4 + 3], a.w);
}

// ---------------------------------------------------------------- launch
extern "C" void kernel_launch(void* const* d_in, const int* in_sizes, int n_in,
                              void* d_out, int out_size, void* d_ws, size_t ws_size,
                              hipStream_t stream)
{
    const float* feats  = (const float*)d_in[0];
    const float* hidden = (const float*)d_in[1];
    const float* Wk     = (const float*)d_in[2];
    const float* Wb     = (const float*)d_in[3];
    const float* Uk     = (const float*)d_in[4];
    const float* Ub     = (const float*)d_in[5];
    const float* Vk     = (const float*)d_in[6];
    // d_in[7] = Vb: constant logit shift, cancels in softmax.

    float* out       = (float*)d_out;
    float* ctx_out_p = out;               // [32*512]  fp32 (atomic target)
    float* aw_out_p  = out + 16384;       // [32*2048] fp32

    char* ws = (char*)d_ws;
    float*    uh  = (float*)ws;                      // 64 KB
    ushort_t* WkT = (ushort_t*)(ws + 65536);         // 512 KB
    float*    lg  = (float*)(ws + 589824);           // 256 KB

    prep_all <<<576, 256, 0, stream>>>(hidden, Uk, Ub, Wb, Wk, uh, WkT, ctx_out_p);
    attn_gemm<<<512, 1024, 0, stream>>>(feats, WkT, uh, Vk, lg);
    softmax_k<<<32,  256, 0, stream>>>(lg, aw_out_p);
    context_k<<<512, 256, 0, stream>>>(feats, aw_out_p, ctx_out_p);
}

// Round 8
// 257.904 us; speedup vs baseline: 1.2750x; 1.0170x over previous
//
#include <hip/hip_runtime.h>
#include <stdint.h>

// Bahdanau additive attention, MI355X / gfx950.
// Inputs fp32, outputs fp32 (ctx[32*512] ++ aw[32*2048]).
// B=32, T=2048, D=512, U=512.  M = B*T = 65536.
//
// R8: B LDS layout XOR-swizzled (source-address permutation — global_load_lds
//     dest must stay lane-contiguous) to kill the 8-way ds_read bank conflict
//     found in R7 (SQ_LDS_BANK_CONFLICT=4.7M). Bank = 16*(lc&1)+4*(quad^swz)
//     -> 2-way = free. Everything else unchanged from R7.

typedef unsigned short ushort_t;
typedef __attribute__((ext_vector_type(8))) short short8;
typedef __attribute__((ext_vector_type(4))) float f32x4;
typedef __attribute__((ext_vector_type(2))) float float2v;
typedef __attribute__((ext_vector_type(2))) __bf16 bf162v;

#define GLOBAL_AS __attribute__((address_space(1)))
#define LDS_AS    __attribute__((address_space(3)))

__device__ __forceinline__ ushort_t f2bf(float f) {
    uint32_t u = __builtin_bit_cast(uint32_t, f);
    u = (u + 0x7fffu + ((u >> 16) & 1u)) >> 16;   // RNE
    return (ushort_t)u;
}
__device__ __forceinline__ uint32_t pkbf(float a, float b) {
    bf162v r = __builtin_convertvector((float2v){a, b}, bf162v);
    return __builtin_bit_cast(uint32_t, r);
}

// --------------------------- fused prep: uh GEMV + WkT transpose + ctx zero
// grid 576 = 256 uh | 256 WkT | 64 ctx-zero
__global__ __launch_bounds__(256) void prep_all(
    const float* __restrict__ hidden, const float* __restrict__ Uk,
    const float* __restrict__ Ub, const float* __restrict__ Wb,
    const float* __restrict__ Wk,
    float* __restrict__ uh, ushort_t* __restrict__ WkT,
    float* __restrict__ ctx_out)
{
    const int pb = blockIdx.x;
    if (pb < 256) {
        // uh[b][u] = hidden[b]·Uk[:,u] + Ub[u] + Wb[u]
        const int b  = pb >> 3;
        const int u  = (pb & 7) * 64 + (threadIdx.x & 63);
        const int k0 = (threadIdx.x >> 6) * 128;
        const float* hr = hidden + b * 512;
        float acc = 0.f;
        #pragma unroll 8
        for (int k = k0; k < k0 + 128; ++k)
            acc += hr[k] * Uk[k * 512 + u];
        __shared__ float red[256];
        red[threadIdx.x] = acc;
        __syncthreads();
        if (threadIdx.x < 64) {
            const int ul = threadIdx.x;
            uh[b * 512 + u] = red[ul] + red[ul + 64] + red[ul + 128] + red[ul + 192]
                            + Ub[u] + Wb[u];
        }
    } else if (pb < 512) {
        // WkT[u][d] = bf16(Wk[d][u]) via 32x32 LDS tile
        __shared__ float t[32][33];
        const int blk = pb - 256;
        const int ti = blk >> 4;
        const int tj = blk & 15;
        const int tx = threadIdx.x & 31;
        const int ty = threadIdx.x >> 5;
        #pragma unroll
        for (int q = 0; q < 4; ++q) {
            const int r = ty * 4 + q;
            t[r][tx] = Wk[(ti * 32 + r) * 512 + tj * 32 + tx];
        }
        __syncthreads();
        #pragma unroll
        for (int q = 0; q < 4; ++q) {
            const int r = ty * 4 + q;
            WkT[(tj * 32 + r) * 512 + ti * 32 + tx] = f2bf(t[tx][r]);
        }
    } else {
        ctx_out[(pb - 512) * 256 + threadIdx.x] = 0.f;   // zero ctx in d_out
    }
}

// ------------------------------------------------ fused GEMM+tanh+Vk-dot
// grid 512 M-tiles of 128 rows; 1024 threads = 16 waves (2M x 8N, 64x64 each).
// All N=512 held in acc. A fp32->bf16 in-kernel; B double-buffered + swizzled.
#define APAD 40   // A row stride in shorts (2-way banks = free)
__global__ __launch_bounds__(1024, 4) void attn_gemm(
    const float* __restrict__ feats, const ushort_t* __restrict__ WkT,
    const float* __restrict__ uh, const float* __restrict__ Vk,
    float* __restrict__ lg)
{
    __shared__ __align__(16) short As[2][128 * APAD];
    __shared__ __align__(16) short Bs[2][512 * 32];
    __shared__ float uh_s[512];
    __shared__ float vk_s[512];
    __shared__ float lpart[8][128];

    const int tid  = threadIdx.x;
    const int lane = tid & 63;
    const int quad = lane >> 4;
    const int lc   = lane & 15;
    const int wave = tid >> 6;       // 0..15
    const int wm   = wave >> 3;      // 0..1  (64-row strip)
    const int wn   = wave & 7;       // 0..7  (64-col strip)
    const int m0   = blockIdx.x * 128;
    const int bidx = m0 >> 11;       // batch index (uniform per block)

    if (tid < 512) {
        uh_s[tid] = uh[bidx * 512 + tid];
        vk_s[tid] = Vk[tid];
    }

    const int rowA = tid >> 3;          // 0..127
    const int kAo  = (tid & 7) * 4;     // fp32 k-offset 0..28
    // B staging swizzle: lds slot s of row r holds global k-slot s ^ ((r>>1)&3)
    const int rB0  = tid >> 2;          // rnd 0 row (0..255)
    const int sB   = tid & 3;           // lds k-slot

    f32x4 acc[4][4];
    #pragma unroll
    for (int tm = 0; tm < 4; ++tm)
        #pragma unroll
        for (int tn = 0; tn < 4; ++tn)
            acc[tm][tn] = (f32x4){0.f, 0.f, 0.f, 0.f};

    // ---- prologue: stage chunk 0 into buf 0
    {
        #pragma unroll
        for (int rnd = 0; rnd < 2; ++rnd) {
            const int li = rnd * 1024 + tid;
            const int rB = rnd * 256 + rB0;
            const int kq = (sB ^ ((rB >> 1) & 3)) * 8;
            const ushort_t* gb = WkT + (size_t)rB * 512 + kq;
            __builtin_amdgcn_global_load_lds(
                (const GLOBAL_AS void*)gb, (LDS_AS void*)(Bs[0] + li * 8), 16, 0, 0);
        }
        const f32x4 av = *(const f32x4*)(feats + (size_t)(m0 + rowA) * 512 + kAo);
        uint2 w;
        w.x = pkbf(av.x, av.y);
        w.y = pkbf(av.z, av.w);
        *(uint2*)(As[0] + rowA * APAD + kAo) = w;
    }

    const int swzR = (lc >> 1) & 3;     // fragment-read swizzle (row = ...+lc)

    int buf = 0;
    for (int ks = 0; ks < 16; ++ks) {   // K = 512, BK = 32
        __syncthreads();                // staging of `buf` complete

        f32x4 a_next;
        const bool have = (ks + 1) < 16;
        if (have) {
            const int k0n = (ks + 1) * 32;
            #pragma unroll
            for (int rnd = 0; rnd < 2; ++rnd) {
                const int li = rnd * 1024 + tid;
                const int rB = rnd * 256 + rB0;
                const int kq = (sB ^ ((rB >> 1) & 3)) * 8;
                const ushort_t* gb = WkT + (size_t)rB * 512 + k0n + kq;
                __builtin_amdgcn_global_load_lds(
                    (const GLOBAL_AS void*)gb, (LDS_AS void*)(Bs[buf ^ 1] + li * 8),
                    16, 0, 0);
            }
            a_next = *(const f32x4*)(feats + (size_t)(m0 + rowA) * 512 + k0n + kAo);
        }

        // ---- compute on `buf` (hides the loads above)
        short8 af[4], bfr[4];
        #pragma unroll
        for (int t4 = 0; t4 < 4; ++t4) {
            af[t4]  = *(const short8*)(As[buf] + (wm * 64 + t4 * 16 + lc) * APAD + quad * 8);
            bfr[t4] = *(const short8*)(Bs[buf] + (wn * 64 + t4 * 16 + lc) * 32
                                       + ((quad ^ swzR) * 8));
        }
        #pragma unroll
        for (int tm = 0; tm < 4; ++tm)
            #pragma unroll
            for (int tn = 0; tn < 4; ++tn)
                acc[tm][tn] = __builtin_amdgcn_mfma_f32_16x16x32_bf16(
                    af[tm], bfr[tn], acc[tm][tn], 0, 0, 0);

        if (have) {
            uint2 w;
            w.x = pkbf(a_next.x, a_next.y);
            w.y = pkbf(a_next.z, a_next.w);
            *(uint2*)(As[buf ^ 1] + rowA * APAD + kAo) = w;
        }
        buf ^= 1;
    }

    // epilogue: tanh(acc + uh) * Vk -> per-row partials
    // C/D layout: col = lane&15, row = quad*4 + reg   [m89-verified]
    float rp[16];
    #pragma unroll
    for (int i = 0; i < 16; ++i) rp[i] = 0.f;
    #pragma unroll
    for (int tn = 0; tn < 4; ++tn) {
        const int nl  = wn * 64 + tn * 16 + lc;
        const float uhv = uh_s[nl];
        const float vkv = vk_s[nl];
        #pragma unroll
        for (int tm = 0; tm < 4; ++tm)
            #pragma unroll
            for (int i = 0; i < 4; ++i) {
                const float x = acc[tm][tn][i] + uhv;
                const float e = __expf(2.0f * x);          // tanh = 1 - 2/(e^{2x}+1)
                rp[tm * 4 + i] += (1.0f - 2.0f / (e + 1.0f)) * vkv;
            }
    }
    #pragma unroll
    for (int i = 0; i < 16; ++i) {
        float v = rp[i];
        v += __shfl_xor(v, 1, 64);
        v += __shfl_xor(v, 2, 64);
        v += __shfl_xor(v, 4, 64);
        v += __shfl_xor(v, 8, 64);
        rp[i] = v;
    }
    if (lc == 0) {
        #pragma unroll
        for (int tm = 0; tm < 4; ++tm)
            #pragma unroll
            for (int i = 0; i < 4; ++i)
                lpart[wn][wm * 64 + tm * 16 + quad * 4 + i] = rp[tm * 4 + i];
    }
    __syncthreads();
    if (tid < 128) {
        float s = 0.f;
        #pragma unroll
        for (int j = 0; j < 8; ++j) s += lpart[j][tid];
        lg[m0 + tid] = s;
    }
}

// ---------------------------------------------------------------- softmax
__global__ __launch_bounds__(256) void softmax_k(
    const float* __restrict__ lg, float* __restrict__ aw_out)
{
    const int b = blockIdx.x, tid = threadIdx.x;
    const float* p = lg + b * 2048;
    float v[8];
    #pragma unroll
    for (int i = 0; i < 8; ++i) v[i] = p[tid + i * 256];
    float mx = -1e30f;
    #pragma unroll
    for (int i = 0; i < 8; ++i) mx = fmaxf(mx, v[i]);
    #pragma unroll
    for (int off = 32; off >= 1; off >>= 1) mx = fmaxf(mx, __shfl_xor(mx, off, 64));
    __shared__ float redm[4], reds[4];
    const int wv = tid >> 6, ln = tid & 63;
    if (ln == 0) redm[wv] = mx;
    __syncthreads();
    mx = fmaxf(fmaxf(redm[0], redm[1]), fmaxf(redm[2], redm[3]));
    float s = 0.f;
    #pragma unroll
    for (int i = 0; i < 8; ++i) { v[i] = __expf(v[i] - mx); s += v[i]; }
    #pragma unroll
    for (int off = 32; off >= 1; off >>= 1) s += __shfl_xor(s, off, 64);
    if (ln == 0) reds[wv] = s;
    __syncthreads();
    s = reds[0] + reds[1] + reds[2] + reds[3];
    const float inv = 1.0f / s;
    #pragma unroll
    for (int i = 0; i < 8; ++i)
        aw_out[b * 2048 + tid + i * 256] = v[i] * inv;
}

// ------------------------------------------------------- context reduction
// grid 512 = 32 b x 16 t-chunks(128); thread: float4 over d, 64 t's.
__global__ __launch_bounds__(256) void context_k(
    const float* __restrict__ feats, const float* __restrict__ aw,
    float* __restrict__ ctx_out)
{
    const int b  = blockIdx.x >> 4;
    const int t0 = (blockIdx.x & 15) * 128 + (threadIdx.x >> 7) * 64;
    const int d4 = (threadIdx.x & 127) * 4;
    const float* wp = aw + b * 2048 + t0;
    const float* fp = feats + (size_t)(b * 2048 + t0) * 512 + d4;
    f32x4 a = (f32x4){0.f, 0.f, 0.f, 0.f};
    #pragma unroll 4
    for (int tt = 0; tt < 64; ++tt) {
        const float w = wp[tt];
        const f32x4 f = *(const f32x4*)(fp + (size_t)tt * 512);
        a.x += w * f.x; a.y += w * f.y; a.z += w * f.z; a.w += w * f.w;
    }
    atomicAdd(&ctx_out[b * 512 + d4],     a.x);
    atomicAdd(&ctx_out[b * 512 + d4 + 1], a.y);
    atomicAdd(&ctx_out[b * 512 + d4 + 2], a.z);
    atomicAdd(&ctx_out[b * 512 + d4 + 3], a.w);
}

// ---------------------------------------------------------------- launch
extern "C" void kernel_launch(void* const* d_in, const int* in_sizes, int n_in,
                              void* d_out, int out_size, void* d_ws, size_t ws_size,
                              hipStream_t stream)
{
    const float* feats  = (const float*)d_in[0];
    const float* hidden = (const float*)d_in[1];
    const float* Wk     = (const float*)d_in[2];
    const float* Wb     = (const float*)d_in[3];
    const float* Uk     = (const float*)d_in[4];
    const float* Ub     = (const float*)d_in[5];
    const float* Vk     = (const float*)d_in[6];
    // d_in[7] = Vb: constant logit shift, cancels in softmax.

    float* out       = (float*)d_out;
    float* ctx_out_p = out;               // [32*512]  fp32 (atomic target)
    float* aw_out_p  = out + 16384;       // [32*2048] fp32

    char* ws = (char*)d_ws;
    float*    uh  = (float*)ws;                      // 64 KB
    ushort_t* WkT = (ushort_t*)(ws + 65536);         // 512 KB
    float*    lg  = (float*)(ws + 589824);           // 256 KB

    prep_all <<<576, 256, 0, stream>>>(hidden, Uk, Ub, Wb, Wk, uh, WkT, ctx_out_p);
    attn_gemm<<<512, 1024, 0, stream>>>(feats, WkT, uh, Vk, lg);
    softmax_k<<<32,  256, 0, stream>>>(lg, aw_out_p);
    context_k<<<512, 256, 0, stream>>>(feats, aw_out_p, ctx_out_p);
}